// Round 5
// baseline (543.014 us; speedup 1.0000x reference)
//
#include <hip/hip_runtime.h>
#include <hip/hip_bf16.h>

typedef unsigned long long u64;
typedef unsigned int uint;
typedef __attribute__((ext_vector_type(8))) short short8;
typedef __attribute__((ext_vector_type(4))) float f32x4;

#define S_STEPS 101
#define BATCH   2048
#define DIN     120
#define HID     200
#define DOUT    12

// round-to-nearest-even f32 -> bf16 (as ushort)
__device__ __forceinline__ ushort f2bf(float f) {
  union { float f; unsigned u; } c; c.f = f;
  unsigned r = (c.u + 0x7FFFu + ((c.u >> 16) & 1u)) >> 16;
  return (ushort)r;
}
__device__ __forceinline__ float bf2f(ushort s) {
  union { unsigned u; float f; } c; c.u = ((unsigned)s) << 16;
  return c.f;
}
// packed f32x2 -> bf16x2 (compiler emits v_cvt_pk_bf16_f32)
__device__ __forceinline__ uint pkbf(float a, float b) {
  __hip_bfloat162 h = __float22bfloat162_rn(make_float2(a, b));
  uint u; __builtin_memcpy(&u, &h, 4);
  return u;
}

// ---------------------------------------------------------------------------
// k_l1: fused layer-1, NO LDS, NO barriers. grid 128 x 256 (4 indep waves).
// Wave w owns h-word w. W1 bf16 B-frags in regs (loaded once). Each lane loads
// its A-fragment directly from global (4 segments x 8 contiguous floats,
// aligned float4 pairs), depth-2 register prefetch (P0 even t / P1 odd t,
// prefetch t+2 during t). bias folded into MFMA C-init. Ballots repacked into
// per-batch h-word masks (layout verified logic from round 4).
// ---------------------------------------------------------------------------
__global__ __launch_bounds__(256) void k_l1(
    const float* __restrict__ x, const float* __restrict__ W1,
    const float* __restrict__ b1, u64* __restrict__ s1m)
{
  const int tid  = threadIdx.x;
  const int lane = tid & 63;
  const int w    = tid >> 6;
  const int b0   = blockIdx.x * 16;
  const int rr   = lane & 15;               // A-row (batch) / B,C-col (h)
  const int hi   = lane >> 4;

  // ---- B fragments (W1 bf16) + bias, in registers ----
  short8 bfrag[4][4];
  float  bv[4];
#pragma unroll
  for (int nt = 0; nt < 4; ++nt) {
    const int n0 = w * 64 + nt * 16 + rr;
    bv[nt] = (n0 < HID) ? b1[n0] : 0.0f;
#pragma unroll
    for (int ks = 0; ks < 4; ++ks) {
      short8 bf = 0;
#pragma unroll
      for (int j = 0; j < 8; ++j) {
        const int k = ks * 32 + hi * 8 + j;
        float wv = (k < DIN && n0 < HID) ? W1[k * HID + n0] : 0.0f;
        bf[j] = (short)f2bf(wv);
      }
      bfrag[nt][ks] = bf;
    }
  }

  // ---- per-lane A-segment base pointers (k0 = ks*32+hi*8, 8|40 so each
  //      8-segment is contiguous within one channel) ----
  const float* bp[4];
#pragma unroll
  for (int ks = 0; ks < 4; ++ks) {
    int k0 = ks * 32 + hi * 8;
    int c = (k0 < DIN) ? (k0 / 40) : 0;
    int m = (k0 < DIN) ? (k0 % 40) : 0;
    bp[ks] = x + ((size_t)(b0 + rr) * 3 + c) * (S_STEPS * 40) + m;
  }
  const bool pad = (hi == 3);               // ks==3 & hi==3 -> k=120..127 pad

  // ---- depth-2 prefetch buffers (zero-init so pad segment is clean) ----
  float4 P0[4][2] = {}; float4 P1[4][2] = {};
#pragma unroll
  for (int ks = 0; ks < 4; ++ks) {
    if (!(ks == 3 && pad)) {
      P0[ks][0] = *(const float4*)(bp[ks]);      P0[ks][1] = *(const float4*)(bp[ks] + 4);
      P1[ks][0] = *(const float4*)(bp[ks] + 40); P1[ks][1] = *(const float4*)(bp[ks] + 44);
    }
  }

  float vst[4][4] = {{0,0,0,0},{0,0,0,0},{0,0,0,0},{0,0,0,0}};
  const int g  = lane >> 2;
  const int r_ = lane & 3;

#define L1_STEP(P, T, PFT)                                                      \
  {                                                                             \
    short8 af[4];                                                               \
    _Pragma("unroll")                                                           \
    for (int ks = 0; ks < 4; ++ks) {                                            \
      union { short8 s; uint u[4]; } cv;                                        \
      cv.u[0] = pkbf(P[ks][0].x, P[ks][0].y);                                   \
      cv.u[1] = pkbf(P[ks][0].z, P[ks][0].w);                                   \
      cv.u[2] = pkbf(P[ks][1].x, P[ks][1].y);                                   \
      cv.u[3] = pkbf(P[ks][1].z, P[ks][1].w);                                   \
      af[ks] = cv.s;                                                            \
    }                                                                           \
    if ((PFT) < S_STEPS) {                                                      \
      _Pragma("unroll")                                                         \
      for (int ks = 0; ks < 4; ++ks)                                            \
        if (!(ks == 3 && pad)) {                                                \
          P[ks][0] = *(const float4*)(bp[ks] + (PFT) * 40);                     \
          P[ks][1] = *(const float4*)(bp[ks] + (PFT) * 40 + 4);                 \
        }                                                                       \
    }                                                                           \
    u64 word = 0;                                                               \
    _Pragma("unroll")                                                           \
    for (int nt = 0; nt < 4; ++nt) {                                            \
      f32x4 acc = {bv[nt], bv[nt], bv[nt], bv[nt]};                             \
      _Pragma("unroll")                                                         \
      for (int ks = 0; ks < 4; ++ks)                                            \
        acc = __builtin_amdgcn_mfma_f32_16x16x32_bf16(af[ks], bfrag[nt][ks],    \
                                                      acc, 0, 0, 0);            \
      u64 q0, q1, q2, q3;                                                       \
      { float v = vst[nt][0]; v = fmaf(0.5f, acc[0] - v, v); bool sp = v >= 1.0f; vst[nt][0] = sp ? 0.f : v; q0 = __ballot(sp); } \
      { float v = vst[nt][1]; v = fmaf(0.5f, acc[1] - v, v); bool sp = v >= 1.0f; vst[nt][1] = sp ? 0.f : v; q1 = __ballot(sp); } \
      { float v = vst[nt][2]; v = fmaf(0.5f, acc[2] - v, v); bool sp = v >= 1.0f; vst[nt][2] = sp ? 0.f : v; q2 = __ballot(sp); } \
      { float v = vst[nt][3]; v = fmaf(0.5f, acc[3] - v, v); bool sp = v >= 1.0f; vst[nt][3] = sp ? 0.f : v; q3 = __ballot(sp); } \
      const u64 sel = (r_ == 0) ? q0 : ((r_ == 1) ? q1 : ((r_ == 2) ? q2 : q3)); \
      word |= ((sel >> (g * 16)) & 0xFFFFull) << (nt * 16);                     \
    }                                                                           \
    if (lane < 16)                                                              \
      s1m[((size_t)(T) * BATCH + b0 + lane) * 4 + w] = word;                    \
  }

#pragma unroll 1
  for (int t = 0; t < S_STEPS - 1; t += 2) {
    L1_STEP(P0, t,     t + 2);
    L1_STEP(P1, t + 1, t + 3);
  }
  L1_STEP(P0, S_STEPS - 1, S_STEPS);   // tail t=100 (prefetched at t=98)
#undef L1_STEP
}

// ---------------------------------------------------------------------------
// k_rec: recurrent layer. grid 256 x 256, 8 batches/block (1 block/CU).
// ALL masks for the block staged to LDS up front (25.9 KB) -> t-loop has no
// global loads in its dependency chain. W bf16 in LDS (80 KB).
// ---------------------------------------------------------------------------
template <bool CNT>
__global__ __launch_bounds__(256) void k_rec(
    const float* __restrict__ W, const float* __restrict__ bias,
    const u64* __restrict__ min_, u64* __restrict__ mout,
    float* __restrict__ cnt)
{
  extern __shared__ char smem[];
  ushort* Ws = (ushort*)smem;                       // 80,000 B
  u64*    Ms = (u64*)(smem + 80000);                // 101*32*8 = 25,856 B
  const int tid  = threadIdx.x;
  const int b0   = blockIdx.x * 8;
  const int lane = tid & 63;
  const bool act = tid < HID;

  for (int idx = tid; idx < HID * HID; idx += 256) Ws[idx] = f2bf(W[idx]);
  {
    const u64* gm = min_ + (size_t)b0 * 4;
    for (int j = tid; j < S_STEPS * 32; j += 256) {
      const int t = j >> 5, r = j & 31;
      Ms[j] = gm[(size_t)t * (BATCH * 4) + r];
    }
  }
  const float bv = act ? bias[tid] : 0.0f;
  float v[8]  = {0,0,0,0,0,0,0,0};
  float c8[8] = {0,0,0,0,0,0,0,0};
  __syncthreads();

#pragma unroll 1
  for (int t = 0; t < S_STEPS; ++t) {
    const u64* mrow = Ms + t * 32;
    u64 mm[8][4];
#pragma unroll
    for (int i = 0; i < 8; ++i)
#pragma unroll
      for (int w = 0; w < 4; ++w) mm[i][w] = mrow[i * 4 + w];

    float acc[8] = {bv, bv, bv, bv, bv, bv, bv, bv};
#pragma unroll
    for (int w = 0; w < 4; ++w) {
      while ((mm[0][w] | mm[1][w] | mm[2][w] | mm[3][w] |
              mm[4][w] | mm[5][w] | mm[6][w] | mm[7][w]) != 0ull) {
#pragma unroll
        for (int i = 0; i < 8; ++i) {
          u64 m = mm[i][w];
          if (m) {                                  // wave-uniform branch
            int k = __builtin_ctzll(m);
            mm[i][w] = m & (m - 1);
            acc[i] += bf2f(Ws[(w * 64 + k) * HID + tid]);
          }
        }
      }
    }

#pragma unroll
    for (int i = 0; i < 8; ++i) {
      float vv = v[i];
      vv = fmaf(0.5f, acc[i] - vv, vv);
      bool sp = act && (vv >= 1.0f);
      v[i] = sp ? 0.0f : vv;
      if (CNT) c8[i] += sp ? 1.0f : 0.0f;
      u64 bal = __ballot(sp);
      if (mout && lane == 0)
        mout[((size_t)t * BATCH + b0 + i) * 4 + (tid >> 6)] = bal;
    }
  }

  if (CNT && act) {
#pragma unroll
    for (int i = 0; i < 8; ++i)
      cnt[(size_t)(b0 + i) * HID + tid] = c8[i];
  }
}

// ---------------------------------------------------------------------------
// k_readout: out = (cnt/101) @ Wr + br, log_softmax over 12 classes.
// ---------------------------------------------------------------------------
__global__ __launch_bounds__(256) void k_readout(
    const float* __restrict__ cnt, const float* __restrict__ Wr,
    const float* __restrict__ br, float* __restrict__ out)
{
  __shared__ float cs[64 * HID];
  __shared__ float Wrs[HID * DOUT];
  __shared__ float brs[DOUT];
  __shared__ float os[64 * DOUT];
  const int tid = threadIdx.x;
  const int b0  = blockIdx.x * 64;

#pragma unroll
  for (int r = 0; r < 50; ++r)
    cs[r * 256 + tid] = cnt[(size_t)b0 * HID + r * 256 + tid];
  for (int idx = tid; idx < HID * DOUT; idx += 256) Wrs[idx] = Wr[idx];
  if (tid < DOUT) brs[tid] = br[tid];
  __syncthreads();

#pragma unroll
  for (int rep = 0; rep < 3; ++rep) {
    int idx = rep * 256 + tid;
    int bl = idx / DOUT, j = idx % DOUT;
    float a = 0.0f;
    for (int k = 0; k < HID; ++k)
      a += cs[bl * HID + k] * Wrs[k * DOUT + j];
    os[idx] = a * (1.0f / 101.0f) + brs[j];
  }
  __syncthreads();

  if (tid < 64) {
    float o[DOUT];
#pragma unroll
    for (int j = 0; j < DOUT; ++j) o[j] = os[tid * DOUT + j];
    float mx = o[0];
#pragma unroll
    for (int j = 1; j < DOUT; ++j) mx = fmaxf(mx, o[j]);
    float s = 0.0f;
#pragma unroll
    for (int j = 0; j < DOUT; ++j) s += expf(o[j] - mx);
    float ls = logf(s);
    float* op = out + (size_t)(b0 + tid) * DOUT;
#pragma unroll
    for (int j = 0; j < DOUT; ++j) op[j] = o[j] - mx - ls;
  }
}

// ---------------------------------------------------------------------------
extern "C" void kernel_launch(void* const* d_in, const int* in_sizes, int n_in,
                              void* d_out, int out_size, void* d_ws, size_t ws_size,
                              hipStream_t stream)
{
  const float* x  = (const float*)d_in[0];
  const float* W1 = (const float*)d_in[1];
  const float* b1 = (const float*)d_in[2];
  const float* W2 = (const float*)d_in[3];
  const float* b2 = (const float*)d_in[4];
  const float* W3 = (const float*)d_in[5];
  const float* b3 = (const float*)d_in[6];
  const float* Wr = (const float*)d_in[7];
  const float* br = (const float*)d_in[8];
  float* out = (float*)d_out;

  char* wsp = (char*)d_ws;
  const size_t mbytes = (size_t)S_STEPS * BATCH * 4 * sizeof(u64); // 6,619,136 B
  u64* s1m   = (u64*)(wsp);
  u64* s2m   = (u64*)(wsp + mbytes);
  float* cnt = (float*)(wsp + 2 * mbytes);   // total ~14.9 MB

  const int rec_lds = 80000 + S_STEPS * 32 * 8;   // 105,856 B
  {
    void (*f2)(const float*, const float*, const u64*, u64*, float*) = k_rec<false>;
    void (*f3)(const float*, const float*, const u64*, u64*, float*) = k_rec<true>;
    hipFuncSetAttribute((const void*)f2, hipFuncAttributeMaxDynamicSharedMemorySize, rec_lds);
    hipFuncSetAttribute((const void*)f3, hipFuncAttributeMaxDynamicSharedMemorySize, rec_lds);
  }

  k_l1<<<BATCH / 16, 256, 0, stream>>>(x, W1, b1, s1m);
  k_rec<false><<<BATCH / 8, 256, rec_lds, stream>>>(W2, b2, s1m, s2m, nullptr);
  k_rec<true ><<<BATCH / 8, 256, rec_lds, stream>>>(W3, b3, s2m, nullptr, cnt);
  k_readout<<<32, 256, 0, stream>>>(cnt, Wr, br, out);
}